// Round 6
// baseline (610.726 us; speedup 1.0000x reference)
//
#include <hip/hip_runtime.h>
#include <hip/hip_bf16.h>
#include <stdint.h>

// Problem constants
#define DIM   1024
#define HID   2732            // divisible by 4 -> float4 chunks never straddle pad
#define HPAD  2816            // HID padded to multiple of 128 (zero-filled logical)
#define NEXP  8
#define NTOK  4096            // B*S
#define NROW  8192            // NTOK * TOPK

typedef __attribute__((ext_vector_type(8))) short bf16x8;   // 8 bf16 = 4 VGPRs
typedef __attribute__((ext_vector_type(4))) float f32x4;

__device__ __forceinline__ unsigned short f2bf(float f) {
    union { float f; uint32_t u; } v; v.f = f;
    uint32_t u = v.u;
    return (unsigned short)((u + 0x7FFFu + ((u >> 16) & 1u)) >> 16);  // RNE
}
__device__ __forceinline__ float bf2f(unsigned short h) {
    union { uint32_t u; float f; } v; v.u = ((uint32_t)h) << 16;
    return v.f;
}

#define ASYNC_CP16(g, l) __builtin_amdgcn_global_load_lds( \
    (const __attribute__((address_space(1))) void*)(g), \
    (__attribute__((address_space(3))) void*)(l), 16, 0, 0)

// pack 8 f32 (two float4, per-half validity) -> 8 bf16
__device__ __forceinline__ bf16x8 pack8(float4 lo, float4 hi, bool vlo, bool vhi) {
    bf16x8 o;
    o[0] = (short)(vlo ? f2bf(lo.x) : 0); o[1] = (short)(vlo ? f2bf(lo.y) : 0);
    o[2] = (short)(vlo ? f2bf(lo.z) : 0); o[3] = (short)(vlo ? f2bf(lo.w) : 0);
    o[4] = (short)(vhi ? f2bf(hi.x) : 0); o[5] = (short)(vhi ? f2bf(hi.y) : 0);
    o[6] = (short)(vhi ? f2bf(hi.z) : 0); o[7] = (short)(vhi ? f2bf(hi.w) : 0);
    return o;
}

// ---------------- routing only (weight conversion is fused into GEMMs) ---
// 4 tokens/block, one wave each.
__global__ void route_kernel(const float* __restrict__ x, const float* __restrict__ Wg,
                             int* __restrict__ counts, int* __restrict__ a_exp,
                             int* __restrict__ a_rank, float* __restrict__ a_w) {
    int wave = threadIdx.x >> 6, lane = threadIdx.x & 63;
    int n = blockIdx.x * 4 + wave;
    const float* xr = x + (size_t)n * DIM + lane * 16;
    float p[NEXP];
#pragma unroll
    for (int e = 0; e < NEXP; ++e) p[e] = 0.f;
#pragma unroll
    for (int i = 0; i < 4; ++i) {
        float4 xv = *(const float4*)(xr + i * 4);
#pragma unroll
        for (int e = 0; e < NEXP; ++e) {
            float4 wv = *(const float4*)(Wg + e * DIM + lane * 16 + i * 4);
            p[e] += xv.x * wv.x + xv.y * wv.y + xv.z * wv.z + xv.w * wv.w;
        }
    }
#pragma unroll
    for (int off = 32; off > 0; off >>= 1)
#pragma unroll
        for (int e = 0; e < NEXP; ++e) p[e] += __shfl_xor(p[e], off);
    if (lane == 0) {
        int i1 = -1, i2 = -1; float m1 = -1e30f, m2 = -1e30f;
#pragma unroll
        for (int e = 0; e < NEXP; ++e) {
            float s = p[e];
            if (s > m1) { m2 = m1; i2 = i1; m1 = s; i1 = e; }
            else if (s > m2) { m2 = s; i2 = e; }
        }
        float e2 = __expf(m2 - m1);           // <= 1
        float inv = 1.f / (1.f + e2);
        int a = n * 2;
        a_exp[a] = i1;  a_w[a] = inv;        a_rank[a] = atomicAdd(&counts[i1], 1);
        a_exp[a+1] = i2; a_w[a+1] = e2 * inv; a_rank[a+1] = atomicAdd(&counts[i2], 1);
    }
}

// gather x rows into per-expert contiguous bf16 buffer; one block per assignment.
__global__ void gather_kernel(const float* __restrict__ x, const int* __restrict__ a_exp,
                              const int* __restrict__ a_rank,
                              const int* __restrict__ counts,
                              unsigned short* __restrict__ XG,
                              int* __restrict__ row_of_a) {
    __shared__ int soff[NEXP];
    if (threadIdx.x == 0) {
        int s = 0;
#pragma unroll
        for (int e = 0; e < NEXP; ++e) { soff[e] = s; s += counts[e]; }
    }
    __syncthreads();
    int a = blockIdx.x, n = a >> 1;
    int row = soff[a_exp[a]] + a_rank[a];
    if (threadIdx.x == 0) row_of_a[a] = row;
    float4 xv = *(const float4*)(x + (size_t)n * DIM + threadIdx.x * 4);
    ushort4 o; o.x = f2bf(xv.x); o.y = f2bf(xv.y); o.z = f2bf(xv.z); o.w = f2bf(xv.w);
    *(ushort4*)(XG + (size_t)row * DIM + threadIdx.x * 4) = o;
}

// ---------------- GEMM1: h = silu(x W1^T) * (x W3^T), W1/W3 read as f32 --
// Block tile 128(M) x 64(N), BK=64. A: bf16 XG via global_load_lds.
// B: f32 -> reg -> f2bf -> ds_write_b128 into the SAME swizzled LDS slots
// the old bf16 ASYNC_CP16 filled (bit-identical staging). Next-step B regs
// prefetched before the barrier so load latency overlaps the MFMA phase.
__global__ __launch_bounds__(256, 2) void gemm1_kernel(
    const unsigned short* __restrict__ XG,   // [NROW][DIM]
    const float* __restrict__ W1,            // [E][HID][DIM] f32
    const float* __restrict__ W3,
    const int* __restrict__ counts,
    unsigned short* __restrict__ Hbuf)       // [NROW][HPAD]
{
    const int e = blockIdx.z, mtile = blockIdx.y, ntile = blockIdx.x;
    const int cnt = counts[e];
    if (mtile * 128 >= cnt) return;
    int rowstart = 0;
    for (int i = 0; i < e; ++i) rowstart += counts[i];
    rowstart += mtile * 128;

    __shared__ __align__(16) unsigned short As[128 * 64];
    __shared__ __align__(16) unsigned short B1s[64 * 64];
    __shared__ __align__(16) unsigned short B3s[64 * 64];

    const int tid = threadIdx.x, lane = tid & 63, wave = tid >> 6;
    const int wm = wave >> 1, wn = wave & 1;
    const int quad = lane >> 4;

    const int srow = tid >> 3;
    const int scol = (((tid & 7) ^ (srow & 7)) * 8);
    const unsigned short* ag[4];
#pragma unroll
    for (int r = 0; r < 4; ++r) {
        int grow = rowstart + r * 32 + srow;
        if (grow > NROW - 1) grow = NROW - 1;         // clamp: junk rows discarded at store
        ag[r] = XG + (size_t)grow * DIM + scol;
    }
    // B sources in f32 with row validity (rows >= HID are logical zero-pad)
    bool rv[2]; const float* bg1[2]; const float* bg3[2];
#pragma unroll
    for (int r = 0; r < 2; ++r) {
        int grow = ntile * 64 + r * 32 + srow;
        rv[r] = (grow < HID);
        int gc = rv[r] ? grow : 0;
        bg1[r] = W1 + (size_t)e * HID * DIM + (size_t)gc * DIM + scol;
        bg3[r] = W3 + (size_t)e * HID * DIM + (size_t)gc * DIM + scol;
    }

    f32x4 acc1[4][2], acc3[4][2];
#pragma unroll
    for (int i = 0; i < 4; ++i)
#pragma unroll
        for (int j = 0; j < 2; ++j) {
            acc1[i][j] = (f32x4){0.f, 0.f, 0.f, 0.f};
            acc3[i][j] = (f32x4){0.f, 0.f, 0.f, 0.f};
        }

    // prologue: B regs for kk=0
    float4 b1lo[2], b1hi[2], b3lo[2], b3hi[2];
#pragma unroll
    for (int r = 0; r < 2; ++r) {
        b1lo[r] = *(const float4*)(bg1[r]);     b1hi[r] = *(const float4*)(bg1[r] + 4);
        b3lo[r] = *(const float4*)(bg3[r]);     b3hi[r] = *(const float4*)(bg3[r] + 4);
    }

    for (int kk = 0; kk < DIM / 64; ++kk) {
        const int k0 = kk * 64;
#pragma unroll
        for (int r = 0; r < 4; ++r)
            ASYNC_CP16(ag[r] + k0, &As[r * 2048 + tid * 8]);
        // convert + stage current B
#pragma unroll
        for (int r = 0; r < 2; ++r) {
            *(bf16x8*)&B1s[r * 2048 + tid * 8] = pack8(b1lo[r], b1hi[r], rv[r], rv[r]);
            *(bf16x8*)&B3s[r * 2048 + tid * 8] = pack8(b3lo[r], b3hi[r], rv[r], rv[r]);
        }
        // prefetch next-step B regs (overlaps barrier + MFMA phase)
        if (kk < DIM / 64 - 1) {
            const int k1 = k0 + 64;
#pragma unroll
            for (int r = 0; r < 2; ++r) {
                b1lo[r] = *(const float4*)(bg1[r] + k1); b1hi[r] = *(const float4*)(bg1[r] + k1 + 4);
                b3lo[r] = *(const float4*)(bg3[r] + k1); b3hi[r] = *(const float4*)(bg3[r] + k1 + 4);
            }
        }
        __syncthreads();
#pragma unroll
        for (int ks = 0; ks < 2; ++ks) {
            const int cbase = ks * 4 + quad;            // chunk index 0..7
            bf16x8 af[4], b1f[2], b3f[2];
#pragma unroll
            for (int i = 0; i < 4; ++i) {
                int rl = wm * 64 + i * 16 + (lane & 15);
                af[i] = *(const bf16x8*)&As[rl * 64 + ((cbase ^ (rl & 7)) * 8)];
            }
#pragma unroll
            for (int j = 0; j < 2; ++j) {
                int rl1 = wn * 32 + j * 16 + (lane & 15);
                b1f[j] = *(const bf16x8*)&B1s[rl1 * 64 + ((cbase ^ (rl1 & 7)) * 8)];
                b3f[j] = *(const bf16x8*)&B3s[rl1 * 64 + ((cbase ^ (rl1 & 7)) * 8)];
            }
#pragma unroll
            for (int i = 0; i < 4; ++i)
#pragma unroll
                for (int j = 0; j < 2; ++j) {
                    acc1[i][j] = __builtin_amdgcn_mfma_f32_16x16x32_bf16(af[i], b1f[j], acc1[i][j], 0, 0, 0);
                    acc3[i][j] = __builtin_amdgcn_mfma_f32_16x16x32_bf16(af[i], b3f[j], acc3[i][j], 0, 0, 0);
                }
        }
        __syncthreads();
    }

    int mvalid = cnt - mtile * 128; if (mvalid > 128) mvalid = 128;
#pragma unroll
    for (int i = 0; i < 4; ++i)
#pragma unroll
        for (int r = 0; r < 4; ++r) {
            int rl = wm * 64 + i * 16 + quad * 4 + r;
            if (rl < mvalid) {
                size_t rowg = (size_t)(rowstart + rl);
#pragma unroll
                for (int j = 0; j < 2; ++j) {
                    float v1 = acc1[i][j][r], v3 = acc3[i][j][r];
                    float s = v1 / (1.f + __expf(-v1));      // silu
                    Hbuf[rowg * HPAD + ntile * 64 + wn * 32 + j * 16 + (lane & 15)] = f2bf(s * v3);
                }
            }
        }
}

// ---------------- GEMM2: y = h W2^T, W2 read as f32 ----------------------
// Block tile 128(M) x 128(N), BK=64, K=HPAD (cols >= HID are logical zeros).
// A: Hbuf bf16 via global_load_lds. B: W2 f32 reg-staged like gemm1.
__global__ __launch_bounds__(256, 2) void gemm2_kernel(
    const unsigned short* __restrict__ Hbuf, // [NROW][HPAD]
    const float* __restrict__ W2,            // [E][DIM][HID] f32 (unpadded)
    const int* __restrict__ counts,
    unsigned short* __restrict__ Ybuf)       // [NROW][DIM] bf16
{
    const int e = blockIdx.z, mtile = blockIdx.y, ntile = blockIdx.x;
    const int cnt = counts[e];
    if (mtile * 128 >= cnt) return;
    int rowstart = 0;
    for (int i = 0; i < e; ++i) rowstart += counts[i];
    rowstart += mtile * 128;

    __shared__ __align__(16) unsigned short As[128 * 64];
    __shared__ __align__(16) unsigned short Bs[128 * 64];

    const int tid = threadIdx.x, lane = tid & 63, wave = tid >> 6;
    const int wm = wave >> 1, wn = wave & 1;
    const int quad = lane >> 4;

    const int srow = tid >> 3;
    const int scol = (((tid & 7) ^ (srow & 7)) * 8);
    const unsigned short* ag[4]; const float* bg[4];
#pragma unroll
    for (int r = 0; r < 4; ++r) {
        int grow = rowstart + r * 32 + srow;
        if (grow > NROW - 1) grow = NROW - 1;
        ag[r] = Hbuf + (size_t)grow * HPAD + scol;
        bg[r] = W2 + (size_t)e * DIM * HID + (size_t)(ntile * 128 + r * 32 + srow) * HID;
    }

    f32x4 acc[4][4];
#pragma unroll
    for (int i = 0; i < 4; ++i)
#pragma unroll
        for (int j = 0; j < 4; ++j) acc[i][j] = (f32x4){0.f, 0.f, 0.f, 0.f};

    // prologue: B regs for kk=0 (c = scol, always < HID)
    float4 blo[4], bhi[4];
#pragma unroll
    for (int r = 0; r < 4; ++r) {
        blo[r] = *(const float4*)(bg[r] + scol);
        bhi[r] = *(const float4*)(bg[r] + scol + 4);
    }

    for (int kk = 0; kk < HPAD / 64; ++kk) {
        const int k0 = kk * 64;
        const int c = k0 + scol;
        const bool vlo = (c < HID), vhi = (c + 4 < HID);   // HID%4==0: no straddle
#pragma unroll
        for (int r = 0; r < 4; ++r)
            ASYNC_CP16(ag[r] + k0, &As[r * 2048 + tid * 8]);
#pragma unroll
        for (int r = 0; r < 4; ++r)
            *(bf16x8*)&Bs[r * 2048 + tid * 8] = pack8(blo[r], bhi[r], vlo, vhi);
        if (kk < HPAD / 64 - 1) {
            const int cn = c + 64;
            const int alo = (cn < HID) ? cn : 0;
            const int ahi = (cn + 4 < HID) ? cn + 4 : 0;
#pragma unroll
            for (int r = 0; r < 4; ++r) {
                blo[r] = *(const float4*)(bg[r] + alo);
                bhi[r] = *(const float4*)(bg[r] + ahi);
            }
        }
        __syncthreads();
#pragma unroll
        for (int ks = 0; ks < 2; ++ks) {
            const int cbase = ks * 4 + quad;
            bf16x8 af[4], bf[4];
#pragma unroll
            for (int i = 0; i < 4; ++i) {
                int rla = wm * 64 + i * 16 + (lane & 15);
                int rlb = wn * 64 + i * 16 + (lane & 15);
                af[i] = *(const bf16x8*)&As[rla * 64 + ((cbase ^ (rla & 7)) * 8)];
                bf[i] = *(const bf16x8*)&Bs[rlb * 64 + ((cbase ^ (rlb & 7)) * 8)];
            }
#pragma unroll
            for (int i = 0; i < 4; ++i)
#pragma unroll
                for (int j = 0; j < 4; ++j)
                    acc[i][j] = __builtin_amdgcn_mfma_f32_16x16x32_bf16(af[i], bf[j], acc[i][j], 0, 0, 0);
        }
        __syncthreads();
    }

    int mvalid = cnt - mtile * 128; if (mvalid > 128) mvalid = 128;
#pragma unroll
    for (int i = 0; i < 4; ++i)
#pragma unroll
        for (int r = 0; r < 4; ++r) {
            int rl = wm * 64 + i * 16 + quad * 4 + r;
            if (rl < mvalid) {
                int rowg = rowstart + rl;
                unsigned short* yrow = Ybuf + (size_t)rowg * DIM + ntile * 128 + wn * 64 + (lane & 15);
#pragma unroll
                for (int j = 0; j < 4; ++j)
                    yrow[j * 16] = f2bf(acc[i][j][r]);
            }
        }
}

// ---------------- combine: out[n] = w0*Y[row0] + w1*Y[row1] --------------
__global__ void combine_kernel(const unsigned short* __restrict__ Ybuf,
                               const int* __restrict__ row_of_a,
                               const float* __restrict__ a_w,
                               float* __restrict__ out) {
    int n = blockIdx.x, t = threadIdx.x;                 // 256 threads, DIM/4
    int r0 = row_of_a[2 * n], r1 = row_of_a[2 * n + 1];
    float w0 = a_w[2 * n], w1 = a_w[2 * n + 1];
    ushort4 y0 = *(const ushort4*)(Ybuf + (size_t)r0 * DIM + t * 4);
    ushort4 y1 = *(const ushort4*)(Ybuf + (size_t)r1 * DIM + t * 4);
    float4 o;
    o.x = w0 * bf2f(y0.x) + w1 * bf2f(y1.x);
    o.y = w0 * bf2f(y0.y) + w1 * bf2f(y1.y);
    o.z = w0 * bf2f(y0.z) + w1 * bf2f(y1.z);
    o.w = w0 * bf2f(y0.w) + w1 * bf2f(y1.w);
    *(float4*)(out + (size_t)n * DIM + t * 4) = o;
}

// ---------------- launch -------------------------------------------------
extern "C" void kernel_launch(void* const* d_in, const int* in_sizes, int n_in,
                              void* d_out, int out_size, void* d_ws, size_t ws_size,
                              hipStream_t stream) {
    const float* x  = (const float*)d_in[0];
    const float* Wg = (const float*)d_in[1];
    const float* W1 = (const float*)d_in[2];
    const float* W2 = (const float*)d_in[3];
    const float* W3 = (const float*)d_in[4];
    float* out = (float*)d_out;

    char* ws = (char*)d_ws;
    size_t off = 0;
    auto alloc = [&](size_t bytes) -> void* {
        void* p = ws + off;
        off = (off + bytes + 255) & ~(size_t)255;
        return p;
    };
    int*   counts      = (int*)alloc(NEXP * 4);
    int*   a_exp       = (int*)alloc(NROW * 4);
    int*   a_rank      = (int*)alloc(NROW * 4);
    float* a_w         = (float*)alloc(NROW * 4);
    int*   row_of_a    = (int*)alloc(NROW * 4);
    unsigned short* XG   = (unsigned short*)alloc((size_t)NROW * DIM * 2);
    unsigned short* Hbuf = (unsigned short*)alloc((size_t)NROW * HPAD * 2);
    unsigned short* Ybuf = (unsigned short*)alloc((size_t)NROW * DIM * 2);

    hipMemsetAsync(counts, 0, NEXP * 4, stream);

    route_kernel<<<NTOK / 4, 256, 0, stream>>>(x, Wg, counts, a_exp, a_rank, a_w);
    gather_kernel<<<NROW, 256, 0, stream>>>(x, a_exp, a_rank, counts, XG, row_of_a);

    gemm1_kernel<<<dim3(HPAD / 64, 64, NEXP), 256, 0, stream>>>(
        XG, W1, W3, counts, Hbuf);
    gemm2_kernel<<<dim3(DIM / 128, 64, NEXP), 256, 0, stream>>>(
        Hbuf, W2, counts, Ybuf);
    combine_kernel<<<NTOK, 256, 0, stream>>>(Ybuf, row_of_a, a_w, out);
}

// Round 7
// 595.209 us; speedup vs baseline: 1.0261x; 1.0261x over previous
//
#include <hip/hip_runtime.h>
#include <hip/hip_bf16.h>
#include <stdint.h>

// Problem constants
#define DIM   1024
#define HID   2732
#define HPAD  2816            // HID padded to multiple of 128 (zero-filled)
#define NEXP  8
#define NTOK  4096            // B*S
#define NROW  8192            // NTOK * TOPK
#define CONV_U 2883584u       // 8-elem units per matrix = E*HPAD*DIM/8
#define CONV_BLOCKS 4096

typedef __attribute__((ext_vector_type(8))) short bf16x8;   // 8 bf16 = 4 VGPRs
typedef __attribute__((ext_vector_type(4))) float f32x4;

__device__ __forceinline__ unsigned short f2bf(float f) {
    union { float f; uint32_t u; } v; v.f = f;
    uint32_t u = v.u;
    return (unsigned short)((u + 0x7FFFu + ((u >> 16) & 1u)) >> 16);  // RNE
}
__device__ __forceinline__ float bf2f(unsigned short h) {
    union { uint32_t u; float f; } v; v.u = ((uint32_t)h) << 16;
    return v.f;
}

#define ASYNC_CP16(g, l) __builtin_amdgcn_global_load_lds( \
    (const __attribute__((address_space(1))) void*)(g), \
    (__attribute__((address_space(3))) void*)(l), 16, 0, 0)

// pack 8 f32 (two float4, per-half validity) -> 8 bf16
__device__ __forceinline__ bf16x8 pack8(float4 lo, float4 hi, bool vlo, bool vhi) {
    bf16x8 o;
    o[0] = (short)(vlo ? f2bf(lo.x) : 0); o[1] = (short)(vlo ? f2bf(lo.y) : 0);
    o[2] = (short)(vlo ? f2bf(lo.z) : 0); o[3] = (short)(vlo ? f2bf(lo.w) : 0);
    o[4] = (short)(vhi ? f2bf(hi.x) : 0); o[5] = (short)(vhi ? f2bf(hi.y) : 0);
    o[6] = (short)(vhi ? f2bf(hi.z) : 0); o[7] = (short)(vhi ? f2bf(hi.w) : 0);
    return o;
}

// ---------------- weight conversion: 8-elem units, 16-B stores -----------
// A/B on the one axis untested by rounds 0/3/4/5 (all stored 8 B/lane):
// each thread converts 8 CONTIGUOUS f32 (2x float4 load = 32 B) into ONE
// 16-B bf16x8 store. Grid-stride, 4096 blocks.
// unit o8 for W1/W3: d8 = o8&127, hp = (o8>>7)%HPAD, e = (o8>>7)/HPAD
// unit o8 for W2:    h8 = o8%352, d = (o8/352)&1023, e = o8/352/1024
__global__ void conv_kernel(const float* __restrict__ W1, const float* __restrict__ W3,
                            const float* __restrict__ W2,
                            unsigned short* __restrict__ W1b,
                            unsigned short* __restrict__ W3b,
                            unsigned short* __restrict__ W2b) {
    const uint32_t stride = gridDim.x * blockDim.x;
    for (uint32_t u = blockIdx.x * blockDim.x + threadIdx.x; u < 3u * CONV_U; u += stride) {
        if (u < 2u * CONV_U) {
            // W1 or W3
            const float* src = (u < CONV_U) ? W1 : W3;
            unsigned short* dst = (u < CONV_U) ? W1b : W3b;
            uint32_t o8 = (u < CONV_U) ? u : u - CONV_U;
            uint32_t d8 = o8 & 127u;
            uint32_t rest = o8 >> 7;
            uint32_t hp = rest % HPAD;
            uint32_t e  = rest / HPAD;
            bool valid = hp < HID;
            size_t s = ((size_t)e * HID + (valid ? hp : 0u)) * DIM + d8 * 8u;
            float4 lo = *(const float4*)(src + s);
            float4 hi = *(const float4*)(src + s + 4);
            *(bf16x8*)(dst + (size_t)o8 * 8) = pack8(lo, hi, valid, valid);
        } else {
            uint32_t o8 = u - 2u * CONV_U;
            uint32_t h8 = o8 % 352u;               // HPAD/8
            uint32_t rest = o8 / 352u;
            uint32_t d = rest & 1023u;
            uint32_t e = rest >> 10;
            uint32_t hbase = h8 * 8u;
            bool vlo = hbase < HID;                // h8 <= 341
            bool vhi = hbase + 8u <= HID;          // h8 <= 340
            size_t s = ((size_t)e * DIM + d) * HID + (vlo ? hbase : 0u);
            float4 lo = *(const float4*)(W2 + s);
            float4 hi = *(const float4*)(W2 + (vhi ? s + 4 : s));  // clamp avoids OOB at row end
            *(bf16x8*)(W2b + (size_t)o8 * 8) = pack8(lo, hi, vlo, vhi);
        }
    }
}

// ---------------- routing: 4 tokens/block, one wave each -----------------
__global__ void route_kernel(const float* __restrict__ x, const float* __restrict__ Wg,
                             int* __restrict__ counts, int* __restrict__ a_exp,
                             int* __restrict__ a_rank, float* __restrict__ a_w) {
    int wave = threadIdx.x >> 6, lane = threadIdx.x & 63;
    int n = blockIdx.x * 4 + wave;
    const float* xr = x + (size_t)n * DIM + lane * 16;
    float p[NEXP];
#pragma unroll
    for (int e = 0; e < NEXP; ++e) p[e] = 0.f;
#pragma unroll
    for (int i = 0; i < 4; ++i) {
        float4 xv = *(const float4*)(xr + i * 4);
#pragma unroll
        for (int e = 0; e < NEXP; ++e) {
            float4 wv = *(const float4*)(Wg + e * DIM + lane * 16 + i * 4);
            p[e] += xv.x * wv.x + xv.y * wv.y + xv.z * wv.z + xv.w * wv.w;
        }
    }
#pragma unroll
    for (int off = 32; off > 0; off >>= 1)
#pragma unroll
        for (int e = 0; e < NEXP; ++e) p[e] += __shfl_xor(p[e], off);
    if (lane == 0) {
        int i1 = -1, i2 = -1; float m1 = -1e30f, m2 = -1e30f;
#pragma unroll
        for (int e = 0; e < NEXP; ++e) {
            float s = p[e];
            if (s > m1) { m2 = m1; i2 = i1; m1 = s; i1 = e; }
            else if (s > m2) { m2 = s; i2 = e; }
        }
        float e2 = __expf(m2 - m1);           // <= 1
        float inv = 1.f / (1.f + e2);
        int a = n * 2;
        a_exp[a] = i1;  a_w[a] = inv;        a_rank[a] = atomicAdd(&counts[i1], 1);
        a_exp[a+1] = i2; a_w[a+1] = e2 * inv; a_rank[a+1] = atomicAdd(&counts[i2], 1);
    }
}

// gather x rows into per-expert contiguous bf16 buffer; one block per assignment.
__global__ void gather_kernel(const float* __restrict__ x, const int* __restrict__ a_exp,
                              const int* __restrict__ a_rank,
                              const int* __restrict__ counts,
                              unsigned short* __restrict__ XG,
                              int* __restrict__ row_of_a) {
    __shared__ int soff[NEXP];
    if (threadIdx.x == 0) {
        int s = 0;
#pragma unroll
        for (int e = 0; e < NEXP; ++e) { soff[e] = s; s += counts[e]; }
    }
    __syncthreads();
    int a = blockIdx.x, n = a >> 1;
    int row = soff[a_exp[a]] + a_rank[a];
    if (threadIdx.x == 0) row_of_a[a] = row;
    float4 xv = *(const float4*)(x + (size_t)n * DIM + threadIdx.x * 4);
    ushort4 o; o.x = f2bf(xv.x); o.y = f2bf(xv.y); o.z = f2bf(xv.z); o.w = f2bf(xv.w);
    *(ushort4*)(XG + (size_t)row * DIM + threadIdx.x * 4) = o;
}

// ---------------- GEMM1: h = silu(x W1^T) * (x W3^T) ---------------------
// Block tile 128(M) x 64(N), BK=64. 4 waves, each 64x32, dual accumulators.
// LDS XOR-swizzle: global chunk c of tile-row r stored at chunk slot c^(r&7).
__global__ __launch_bounds__(256, 2) void gemm1_kernel(
    const unsigned short* __restrict__ XG,   // [NROW][DIM]
    const unsigned short* __restrict__ W1b,  // [E][HPAD][DIM]
    const unsigned short* __restrict__ W3b,
    const int* __restrict__ counts,
    unsigned short* __restrict__ Hbuf)       // [NROW][HPAD]
{
    const int e = blockIdx.z, mtile = blockIdx.y, ntile = blockIdx.x;
    const int cnt = counts[e];
    if (mtile * 128 >= cnt) return;
    int rowstart = 0;
    for (int i = 0; i < e; ++i) rowstart += counts[i];
    rowstart += mtile * 128;

    __shared__ __align__(16) unsigned short As[128 * 64];
    __shared__ __align__(16) unsigned short B1s[64 * 64];
    __shared__ __align__(16) unsigned short B3s[64 * 64];

    const int tid = threadIdx.x, lane = tid & 63, wave = tid >> 6;
    const int wm = wave >> 1, wn = wave & 1;
    const int quad = lane >> 4;

    const unsigned short* w1e = W1b + (size_t)e * HPAD * DIM;
    const unsigned short* w3e = W3b + (size_t)e * HPAD * DIM;

    const int srow = tid >> 3;
    const int scol = (((tid & 7) ^ (srow & 7)) * 8);
    const unsigned short* ag[4];
#pragma unroll
    for (int r = 0; r < 4; ++r) {
        int grow = rowstart + r * 32 + srow;
        if (grow > NROW - 1) grow = NROW - 1;         // clamp: junk rows discarded at store
        ag[r] = XG + (size_t)grow * DIM + scol;
    }
    const unsigned short* bg1[2]; const unsigned short* bg3[2];
#pragma unroll
    for (int r = 0; r < 2; ++r) {
        int grow = ntile * 64 + r * 32 + srow;
        bg1[r] = w1e + (size_t)grow * DIM + scol;
        bg3[r] = w3e + (size_t)grow * DIM + scol;
    }

    f32x4 acc1[4][2], acc3[4][2];
#pragma unroll
    for (int i = 0; i < 4; ++i)
#pragma unroll
        for (int j = 0; j < 2; ++j) {
            acc1[i][j] = (f32x4){0.f, 0.f, 0.f, 0.f};
            acc3[i][j] = (f32x4){0.f, 0.f, 0.f, 0.f};
        }

    for (int kk = 0; kk < DIM / 64; ++kk) {
        const int k0 = kk * 64;
#pragma unroll
        for (int r = 0; r < 4; ++r)
            ASYNC_CP16(ag[r] + k0, &As[r * 2048 + tid * 8]);
#pragma unroll
        for (int r = 0; r < 2; ++r) {
            ASYNC_CP16(bg1[r] + k0, &B1s[r * 2048 + tid * 8]);
            ASYNC_CP16(bg3[r] + k0, &B3s[r * 2048 + tid * 8]);
        }
        __syncthreads();
#pragma unroll
        for (int ks = 0; ks < 2; ++ks) {
            const int cbase = ks * 4 + quad;            // chunk index 0..7
            bf16x8 af[4], b1f[2], b3f[2];
#pragma unroll
            for (int i = 0; i < 4; ++i) {
                int rl = wm * 64 + i * 16 + (lane & 15);
                af[i] = *(const bf16x8*)&As[rl * 64 + ((cbase ^ (rl & 7)) * 8)];
            }
#pragma unroll
            for (int j = 0; j < 2; ++j) {
                int rl1 = wn * 32 + j * 16 + (lane & 15);
                b1f[j] = *(const bf16x8*)&B1s[rl1 * 64 + ((cbase ^ (rl1 & 7)) * 8)];
                b3f[j] = *(const bf16x8*)&B3s[rl1 * 64 + ((cbase ^ (rl1 & 7)) * 8)];
            }
#pragma unroll
            for (int i = 0; i < 4; ++i)
#pragma unroll
                for (int j = 0; j < 2; ++j) {
                    acc1[i][j] = __builtin_amdgcn_mfma_f32_16x16x32_bf16(af[i], b1f[j], acc1[i][j], 0, 0, 0);
                    acc3[i][j] = __builtin_amdgcn_mfma_f32_16x16x32_bf16(af[i], b3f[j], acc3[i][j], 0, 0, 0);
                }
        }
        __syncthreads();
    }

    int mvalid = cnt - mtile * 128; if (mvalid > 128) mvalid = 128;
#pragma unroll
    for (int i = 0; i < 4; ++i)
#pragma unroll
        for (int r = 0; r < 4; ++r) {
            int rl = wm * 64 + i * 16 + quad * 4 + r;
            if (rl < mvalid) {
                size_t rowg = (size_t)(rowstart + rl);
#pragma unroll
                for (int j = 0; j < 2; ++j) {
                    float v1 = acc1[i][j][r], v3 = acc3[i][j][r];
                    float s = v1 / (1.f + __expf(-v1));      // silu
                    Hbuf[rowg * HPAD + ntile * 64 + wn * 32 + j * 16 + (lane & 15)] = f2bf(s * v3);
                }
            }
        }
}

// ---------------- GEMM2: y = h W2^T -> Ybuf (bf16, unscaled) -------------
// Block tile 128(M) x 128(N), BK=64, K=HPAD. 4 waves, each 64x64.
__global__ __launch_bounds__(256, 2) void gemm2_kernel(
    const unsigned short* __restrict__ Hbuf, // [NROW][HPAD]
    const unsigned short* __restrict__ W2b,  // [E][DIM][HPAD]
    const int* __restrict__ counts,
    unsigned short* __restrict__ Ybuf)       // [NROW][DIM] bf16
{
    const int e = blockIdx.z, mtile = blockIdx.y, ntile = blockIdx.x;
    const int cnt = counts[e];
    if (mtile * 128 >= cnt) return;
    int rowstart = 0;
    for (int i = 0; i < e; ++i) rowstart += counts[i];
    rowstart += mtile * 128;

    __shared__ __align__(16) unsigned short As[128 * 64];
    __shared__ __align__(16) unsigned short Bs[128 * 64];

    const int tid = threadIdx.x, lane = tid & 63, wave = tid >> 6;
    const int wm = wave >> 1, wn = wave & 1;
    const int quad = lane >> 4;

    const unsigned short* w2e = W2b + (size_t)e * DIM * HPAD;
    const int srow = tid >> 3;
    const int scol = (((tid & 7) ^ (srow & 7)) * 8);
    const unsigned short* ag[4]; const unsigned short* bg[4];
#pragma unroll
    for (int r = 0; r < 4; ++r) {
        int grow = rowstart + r * 32 + srow;
        if (grow > NROW - 1) grow = NROW - 1;
        ag[r] = Hbuf + (size_t)grow * HPAD + scol;
        bg[r] = w2e + (size_t)(ntile * 128 + r * 32 + srow) * HPAD + scol;
    }

    f32x4 acc[4][4];
#pragma unroll
    for (int i = 0; i < 4; ++i)
#pragma unroll
        for (int j = 0; j < 4; ++j) acc[i][j] = (f32x4){0.f, 0.f, 0.f, 0.f};

    for (int kk = 0; kk < HPAD / 64; ++kk) {
        const int k0 = kk * 64;
#pragma unroll
        for (int r = 0; r < 4; ++r) {
            ASYNC_CP16(ag[r] + k0, &As[r * 2048 + tid * 8]);
            ASYNC_CP16(bg[r] + k0, &Bs[r * 2048 + tid * 8]);
        }
        __syncthreads();
#pragma unroll
        for (int ks = 0; ks < 2; ++ks) {
            const int cbase = ks * 4 + quad;
            bf16x8 af[4], bf[4];
#pragma unroll
            for (int i = 0; i < 4; ++i) {
                int rla = wm * 64 + i * 16 + (lane & 15);
                int rlb = wn * 64 + i * 16 + (lane & 15);
                af[i] = *(const bf16x8*)&As[rla * 64 + ((cbase ^ (rla & 7)) * 8)];
                bf[i] = *(const bf16x8*)&Bs[rlb * 64 + ((cbase ^ (rlb & 7)) * 8)];
            }
#pragma unroll
            for (int i = 0; i < 4; ++i)
#pragma unroll
                for (int j = 0; j < 4; ++j)
                    acc[i][j] = __builtin_amdgcn_mfma_f32_16x16x32_bf16(af[i], bf[j], acc[i][j], 0, 0, 0);
        }
        __syncthreads();
    }

    int mvalid = cnt - mtile * 128; if (mvalid > 128) mvalid = 128;
#pragma unroll
    for (int i = 0; i < 4; ++i)
#pragma unroll
        for (int r = 0; r < 4; ++r) {
            int rl = wm * 64 + i * 16 + quad * 4 + r;
            if (rl < mvalid) {
                int rowg = rowstart + rl;
                unsigned short* yrow = Ybuf + (size_t)rowg * DIM + ntile * 128 + wn * 64 + (lane & 15);
#pragma unroll
                for (int j = 0; j < 4; ++j)
                    yrow[j * 16] = f2bf(acc[i][j][r]);
            }
        }
}

// ---------------- combine: out[n] = w0*Y[row0] + w1*Y[row1] --------------
__global__ void combine_kernel(const unsigned short* __restrict__ Ybuf,
                               const int* __restrict__ row_of_a,
                               const float* __restrict__ a_w,
                               float* __restrict__ out) {
    int n = blockIdx.x, t = threadIdx.x;                 // 256 threads, DIM/4
    int r0 = row_of_a[2 * n], r1 = row_of_a[2 * n + 1];
    float w0 = a_w[2 * n], w1 = a_w[2 * n + 1];
    ushort4 y0 = *(const ushort4*)(Ybuf + (size_t)r0 * DIM + t * 4);
    ushort4 y1 = *(const ushort4*)(Ybuf + (size_t)r1 * DIM + t * 4);
    float4 o;
    o.x = w0 * bf2f(y0.x) + w1 * bf2f(y1.x);
    o.y = w0 * bf2f(y0.y) + w1 * bf2f(y1.y);
    o.z = w0 * bf2f(y0.z) + w1 * bf2f(y1.z);
    o.w = w0 * bf2f(y0.w) + w1 * bf2f(y1.w);
    *(float4*)(out + (size_t)n * DIM + t * 4) = o;
}

// ---------------- launch -------------------------------------------------
extern "C" void kernel_launch(void* const* d_in, const int* in_sizes, int n_in,
                              void* d_out, int out_size, void* d_ws, size_t ws_size,
                              hipStream_t stream) {
    const float* x  = (const float*)d_in[0];
    const float* Wg = (const float*)d_in[1];
    const float* W1 = (const float*)d_in[2];
    const float* W2 = (const float*)d_in[3];
    const float* W3 = (const float*)d_in[4];
    float* out = (float*)d_out;

    char* ws = (char*)d_ws;
    size_t off = 0;
    auto alloc = [&](size_t bytes) -> void* {
        void* p = ws + off;
        off = (off + bytes + 255) & ~(size_t)255;
        return p;
    };
    int*   counts      = (int*)alloc(NEXP * 4);
    int*   a_exp       = (int*)alloc(NROW * 4);
    int*   a_rank      = (int*)alloc(NROW * 4);
    float* a_w         = (float*)alloc(NROW * 4);
    int*   row_of_a    = (int*)alloc(NROW * 4);
    unsigned short* XG   = (unsigned short*)alloc((size_t)NROW * DIM * 2);
    unsigned short* Hbuf = (unsigned short*)alloc((size_t)NROW * HPAD * 2);
    unsigned short* W1b  = (unsigned short*)alloc((size_t)NEXP * HPAD * DIM * 2);
    unsigned short* W3b  = (unsigned short*)alloc((size_t)NEXP * HPAD * DIM * 2);
    unsigned short* W2b  = (unsigned short*)alloc((size_t)NEXP * DIM * HPAD * 2);
    // Ybuf bf16 (16.8 MB) aliases W1b (46.1 MB): W1b is dead once gemm1 completes.
    unsigned short* Ybuf = (unsigned short*)W1b;

    hipMemsetAsync(counts, 0, NEXP * 4, stream);

    route_kernel<<<NTOK / 4, 256, 0, stream>>>(x, Wg, counts, a_exp, a_rank, a_w);
    conv_kernel<<<CONV_BLOCKS, 256, 0, stream>>>(W1, W3, W2, W1b, W3b, W2b);
    gather_kernel<<<NROW, 256, 0, stream>>>(x, a_exp, a_rank, counts, XG, row_of_a);

    gemm1_kernel<<<dim3(HPAD / 64, 64, NEXP), 256, 0, stream>>>(
        XG, W1b, W3b, counts, Hbuf);
    gemm2_kernel<<<dim3(DIM / 128, 64, NEXP), 256, 0, stream>>>(
        Hbuf, W2b, counts, Ybuf);
    combine_kernel<<<NTOK, 256, 0, stream>>>(Ybuf, row_of_a, a_w, out);
}

// Round 8
// 586.016 us; speedup vs baseline: 1.0422x; 1.0157x over previous
//
#include <hip/hip_runtime.h>
#include <hip/hip_bf16.h>
#include <stdint.h>

// Problem constants
#define DIM   1024
#define HID   2732
#define HPAD  2816            // HID padded to multiple of 128 (zero-filled)
#define NEXP  8
#define NTOK  4096            // B*S
#define NROW  8192            // NTOK * TOPK
#define U16_PER_MAT 1441792u  // E*HPAD*DIM/16
#define CONV16_BLOCKS 16896   // 3 * U16_PER_MAT / 256
#define PREP_BLOCKS (CONV16_BLOCKS + NTOK / 4)

typedef __attribute__((ext_vector_type(8))) short bf16x8;   // 8 bf16 = 4 VGPRs
typedef __attribute__((ext_vector_type(4))) float f32x4;

__device__ __forceinline__ unsigned short f2bf(float f) {
    union { float f; uint32_t u; } v; v.f = f;
    uint32_t u = v.u;
    return (unsigned short)((u + 0x7FFFu + ((u >> 16) & 1u)) >> 16);  // RNE
}
__device__ __forceinline__ float bf2f(unsigned short h) {
    union { uint32_t u; float f; } v; v.u = ((uint32_t)h) << 16;
    return v.f;
}

#define ASYNC_CP16(g, l) __builtin_amdgcn_global_load_lds( \
    (const __attribute__((address_space(1))) void*)(g), \
    (__attribute__((address_space(3))) void*)(l), 16, 0, 0)

// pack 8 f32 (two f32x4, per-quad validity) -> 8 bf16
__device__ __forceinline__ bf16x8 pack8(f32x4 lo, f32x4 hi, bool vlo, bool vhi) {
    bf16x8 o;
    o[0] = (short)(vlo ? f2bf(lo.x) : 0); o[1] = (short)(vlo ? f2bf(lo.y) : 0);
    o[2] = (short)(vlo ? f2bf(lo.z) : 0); o[3] = (short)(vlo ? f2bf(lo.w) : 0);
    o[4] = (short)(vhi ? f2bf(hi.x) : 0); o[5] = (short)(vhi ? f2bf(hi.y) : 0);
    o[6] = (short)(vhi ? f2bf(hi.z) : 0); o[7] = (short)(vhi ? f2bf(hi.w) : 0);
    return o;
}

// ---------------- prep2: weight conversion (16-elem units) + routing -----
// Width ladder measured: 4-elem/8B-store=1.42 TB/s, 8-elem/16B-store=2.45.
// This round: 16 f32/thread via 4 independent NONTEMPORAL float4 loads
// (dead-after-read f32 source bypasses L3 churn) -> two 16B bf16 stores.
// Routing blocks fused into the same dispatch (ride along free).
// blocks [0, CONV16_BLOCKS)          : conversion, matrix = b / 5632
// blocks [CONV16_BLOCKS, +NTOK/4)    : routing (4 tokens/block, 1 wave each)
__global__ void prep2_kernel(const float* __restrict__ x,  const float* __restrict__ Wg,
                             const float* __restrict__ W1, const float* __restrict__ W2,
                             const float* __restrict__ W3,
                             unsigned short* __restrict__ W1b,
                             unsigned short* __restrict__ W2b,
                             unsigned short* __restrict__ W3b,
                             int* __restrict__ counts, int* __restrict__ a_exp,
                             int* __restrict__ a_rank, float* __restrict__ a_w) {
    int b = blockIdx.x;
    if (b < CONV16_BLOCKS) {
        const int mat = b / 5632;                       // 0=W1 1=W3 2=W2
        const uint32_t o16 = (uint32_t)(b % 5632) * 256u + threadIdx.x;
        if (mat < 2) {
            const float* src = mat ? W3 : W1;
            unsigned short* dst = mat ? W3b : W1b;
            uint32_t d16 = o16 & 63u;                   // DIM/16 = 64
            uint32_t rest = o16 >> 6;
            uint32_t hp = rest % HPAD;
            uint32_t e  = rest / HPAD;
            bool valid = hp < HID;
            const f32x4* s = (const f32x4*)(src + ((size_t)e * HID + (valid ? hp : 0u)) * DIM + d16 * 16u);
            f32x4 v0 = __builtin_nontemporal_load(s);
            f32x4 v1 = __builtin_nontemporal_load(s + 1);
            f32x4 v2 = __builtin_nontemporal_load(s + 2);
            f32x4 v3 = __builtin_nontemporal_load(s + 3);
            unsigned short* d = dst + (size_t)o16 * 16;
            *(bf16x8*)d       = pack8(v0, v1, valid, valid);
            *(bf16x8*)(d + 8) = pack8(v2, v3, valid, valid);
        } else {
            uint32_t h16 = o16 % 176u;                  // HPAD/16
            uint32_t rest = o16 / 176u;
            uint32_t d = rest & 1023u;
            uint32_t e = rest >> 10;
            uint32_t hb = h16 * 16u;
            // per-quad validity (HID%4==0: quads never straddle)
            bool q0 = hb < HID, q1 = hb + 4u < HID, q2 = hb + 8u < HID, q3 = hb + 12u < HID;
            size_t row = ((size_t)e * DIM + d) * HID;
            f32x4 v0 = __builtin_nontemporal_load((const f32x4*)(W2 + row + (q0 ? hb : 0u)));
            f32x4 v1 = __builtin_nontemporal_load((const f32x4*)(W2 + row + (q1 ? hb + 4u : 0u)));
            f32x4 v2 = __builtin_nontemporal_load((const f32x4*)(W2 + row + (q2 ? hb + 8u : 0u)));
            f32x4 v3 = __builtin_nontemporal_load((const f32x4*)(W2 + row + (q3 ? hb + 12u : 0u)));
            unsigned short* dd = W2b + (size_t)o16 * 16;
            *(bf16x8*)dd       = pack8(v0, v1, q0, q1);
            *(bf16x8*)(dd + 8) = pack8(v2, v3, q2, q3);
        }
        return;
    }
    b -= CONV16_BLOCKS;
    // routing: block handles 4 tokens, one wave each
    int wave = threadIdx.x >> 6, lane = threadIdx.x & 63;
    int n = b * 4 + wave;
    const float* xr = x + (size_t)n * DIM + lane * 16;
    float p[NEXP];
#pragma unroll
    for (int e = 0; e < NEXP; ++e) p[e] = 0.f;
#pragma unroll
    for (int i = 0; i < 4; ++i) {
        float4 xv = *(const float4*)(xr + i * 4);
#pragma unroll
        for (int e = 0; e < NEXP; ++e) {
            float4 wv = *(const float4*)(Wg + e * DIM + lane * 16 + i * 4);
            p[e] += xv.x * wv.x + xv.y * wv.y + xv.z * wv.z + xv.w * wv.w;
        }
    }
#pragma unroll
    for (int off = 32; off > 0; off >>= 1)
#pragma unroll
        for (int e = 0; e < NEXP; ++e) p[e] += __shfl_xor(p[e], off);
    if (lane == 0) {
        int i1 = -1, i2 = -1; float m1 = -1e30f, m2 = -1e30f;
#pragma unroll
        for (int e = 0; e < NEXP; ++e) {
            float s = p[e];
            if (s > m1) { m2 = m1; i2 = i1; m1 = s; i1 = e; }
            else if (s > m2) { m2 = s; i2 = e; }
        }
        float e2 = __expf(m2 - m1);           // <= 1
        float inv = 1.f / (1.f + e2);
        int a = n * 2;
        a_exp[a] = i1;  a_w[a] = inv;        a_rank[a] = atomicAdd(&counts[i1], 1);
        a_exp[a+1] = i2; a_w[a+1] = e2 * inv; a_rank[a+1] = atomicAdd(&counts[i2], 1);
    }
}

// gather x rows into per-expert contiguous bf16 buffer.
// 2 assignments/block: each thread converts 8 elems (2 float4 -> one 16B store).
__global__ void gather_kernel(const float* __restrict__ x, const int* __restrict__ a_exp,
                              const int* __restrict__ a_rank,
                              const int* __restrict__ counts,
                              unsigned short* __restrict__ XG,
                              int* __restrict__ row_of_a) {
    __shared__ int soff[NEXP];
    if (threadIdx.x == 0) {
        int s = 0;
#pragma unroll
        for (int e = 0; e < NEXP; ++e) { soff[e] = s; s += counts[e]; }
    }
    __syncthreads();
    int half = threadIdx.x >> 7, t = threadIdx.x & 127;
    int a = blockIdx.x * 2 + half, n = a >> 1;
    int row = soff[a_exp[a]] + a_rank[a];
    if (t == 0) row_of_a[a] = row;
    const f32x4* xp = (const f32x4*)(x + (size_t)n * DIM + t * 8);
    f32x4 lo = xp[0], hi = xp[1];
    *(bf16x8*)(XG + (size_t)row * DIM + t * 8) = pack8(lo, hi, true, true);
}

// ---------------- GEMM1: h = silu(x W1^T) * (x W3^T) ---------------------
// Block tile 128(M) x 64(N), BK=64. 4 waves, each 64x32, dual accumulators.
// LDS XOR-swizzle: global chunk c of tile-row r stored at chunk slot c^(r&7).
__global__ __launch_bounds__(256, 2) void gemm1_kernel(
    const unsigned short* __restrict__ XG,   // [NROW][DIM]
    const unsigned short* __restrict__ W1b,  // [E][HPAD][DIM]
    const unsigned short* __restrict__ W3b,
    const int* __restrict__ counts,
    unsigned short* __restrict__ Hbuf)       // [NROW][HPAD]
{
    const int e = blockIdx.z, mtile = blockIdx.y, ntile = blockIdx.x;
    const int cnt = counts[e];
    if (mtile * 128 >= cnt) return;
    int rowstart = 0;
    for (int i = 0; i < e; ++i) rowstart += counts[i];
    rowstart += mtile * 128;

    __shared__ __align__(16) unsigned short As[128 * 64];
    __shared__ __align__(16) unsigned short B1s[64 * 64];
    __shared__ __align__(16) unsigned short B3s[64 * 64];

    const int tid = threadIdx.x, lane = tid & 63, wave = tid >> 6;
    const int wm = wave >> 1, wn = wave & 1;
    const int quad = lane >> 4;

    const unsigned short* w1e = W1b + (size_t)e * HPAD * DIM;
    const unsigned short* w3e = W3b + (size_t)e * HPAD * DIM;

    const int srow = tid >> 3;
    const int scol = (((tid & 7) ^ (srow & 7)) * 8);
    const unsigned short* ag[4];
#pragma unroll
    for (int r = 0; r < 4; ++r) {
        int grow = rowstart + r * 32 + srow;
        if (grow > NROW - 1) grow = NROW - 1;         // clamp: junk rows discarded at store
        ag[r] = XG + (size_t)grow * DIM + scol;
    }
    const unsigned short* bg1[2]; const unsigned short* bg3[2];
#pragma unroll
    for (int r = 0; r < 2; ++r) {
        int grow = ntile * 64 + r * 32 + srow;
        bg1[r] = w1e + (size_t)grow * DIM + scol;
        bg3[r] = w3e + (size_t)grow * DIM + scol;
    }

    f32x4 acc1[4][2], acc3[4][2];
#pragma unroll
    for (int i = 0; i < 4; ++i)
#pragma unroll
        for (int j = 0; j < 2; ++j) {
            acc1[i][j] = (f32x4){0.f, 0.f, 0.f, 0.f};
            acc3[i][j] = (f32x4){0.f, 0.f, 0.f, 0.f};
        }

    for (int kk = 0; kk < DIM / 64; ++kk) {
        const int k0 = kk * 64;
#pragma unroll
        for (int r = 0; r < 4; ++r)
            ASYNC_CP16(ag[r] + k0, &As[r * 2048 + tid * 8]);
#pragma unroll
        for (int r = 0; r < 2; ++r) {
            ASYNC_CP16(bg1[r] + k0, &B1s[r * 2048 + tid * 8]);
            ASYNC_CP16(bg3[r] + k0, &B3s[r * 2048 + tid * 8]);
        }
        __syncthreads();
#pragma unroll
        for (int ks = 0; ks < 2; ++ks) {
            const int cbase = ks * 4 + quad;            // chunk index 0..7
            bf16x8 af[4], b1f[2], b3f[2];
#pragma unroll
            for (int i = 0; i < 4; ++i) {
                int rl = wm * 64 + i * 16 + (lane & 15);
                af[i] = *(const bf16x8*)&As[rl * 64 + ((cbase ^ (rl & 7)) * 8)];
            }
#pragma unroll
            for (int j = 0; j < 2; ++j) {
                int rl1 = wn * 32 + j * 16 + (lane & 15);
                b1f[j] = *(const bf16x8*)&B1s[rl1 * 64 + ((cbase ^ (rl1 & 7)) * 8)];
                b3f[j] = *(const bf16x8*)&B3s[rl1 * 64 + ((cbase ^ (rl1 & 7)) * 8)];
            }
#pragma unroll
            for (int i = 0; i < 4; ++i)
#pragma unroll
                for (int j = 0; j < 2; ++j) {
                    acc1[i][j] = __builtin_amdgcn_mfma_f32_16x16x32_bf16(af[i], b1f[j], acc1[i][j], 0, 0, 0);
                    acc3[i][j] = __builtin_amdgcn_mfma_f32_16x16x32_bf16(af[i], b3f[j], acc3[i][j], 0, 0, 0);
                }
        }
        __syncthreads();
    }

    int mvalid = cnt - mtile * 128; if (mvalid > 128) mvalid = 128;
#pragma unroll
    for (int i = 0; i < 4; ++i)
#pragma unroll
        for (int r = 0; r < 4; ++r) {
            int rl = wm * 64 + i * 16 + quad * 4 + r;
            if (rl < mvalid) {
                size_t rowg = (size_t)(rowstart + rl);
#pragma unroll
                for (int j = 0; j < 2; ++j) {
                    float v1 = acc1[i][j][r], v3 = acc3[i][j][r];
                    float s = v1 / (1.f + __expf(-v1));      // silu
                    Hbuf[rowg * HPAD + ntile * 64 + wn * 32 + j * 16 + (lane & 15)] = f2bf(s * v3);
                }
            }
        }
}

// ---------------- GEMM2: y = h W2^T -> Ybuf (bf16, unscaled) -------------
// Block tile 128(M) x 128(N), BK=64, K=HPAD. 4 waves, each 64x64.
__global__ __launch_bounds__(256, 2) void gemm2_kernel(
    const unsigned short* __restrict__ Hbuf, // [NROW][HPAD]
    const unsigned short* __restrict__ W2b,  // [E][DIM][HPAD]
    const int* __restrict__ counts,
    unsigned short* __restrict__ Ybuf)       // [NROW][DIM] bf16
{
    const int e = blockIdx.z, mtile = blockIdx.y, ntile = blockIdx.x;
    const int cnt = counts[e];
    if (mtile * 128 >= cnt) return;
    int rowstart = 0;
    for (int i = 0; i < e; ++i) rowstart += counts[i];
    rowstart += mtile * 128;

    __shared__ __align__(16) unsigned short As[128 * 64];
    __shared__ __align__(16) unsigned short Bs[128 * 64];

    const int tid = threadIdx.x, lane = tid & 63, wave = tid >> 6;
    const int wm = wave >> 1, wn = wave & 1;
    const int quad = lane >> 4;

    const unsigned short* w2e = W2b + (size_t)e * DIM * HPAD;
    const int srow = tid >> 3;
    const int scol = (((tid & 7) ^ (srow & 7)) * 8);
    const unsigned short* ag[4]; const unsigned short* bg[4];
#pragma unroll
    for (int r = 0; r < 4; ++r) {
        int grow = rowstart + r * 32 + srow;
        if (grow > NROW - 1) grow = NROW - 1;
        ag[r] = Hbuf + (size_t)grow * HPAD + scol;
        bg[r] = w2e + (size_t)(ntile * 128 + r * 32 + srow) * HPAD + scol;
    }

    f32x4 acc[4][4];
#pragma unroll
    for (int i = 0; i < 4; ++i)
#pragma unroll
        for (int j = 0; j < 4; ++j) acc[i][j] = (f32x4){0.f, 0.f, 0.f, 0.f};

    for (int kk = 0; kk < HPAD / 64; ++kk) {
        const int k0 = kk * 64;
#pragma unroll
        for (int r = 0; r < 4; ++r) {
            ASYNC_CP16(ag[r] + k0, &As[r * 2048 + tid * 8]);
            ASYNC_CP16(bg[r] + k0, &Bs[r * 2048 + tid * 8]);
        }
        __syncthreads();
#pragma unroll
        for (int ks = 0; ks < 2; ++ks) {
            const int cbase = ks * 4 + quad;
            bf16x8 af[4], bf[4];
#pragma unroll
            for (int i = 0; i < 4; ++i) {
                int rla = wm * 64 + i * 16 + (lane & 15);
                int rlb = wn * 64 + i * 16 + (lane & 15);
                af[i] = *(const bf16x8*)&As[rla * 64 + ((cbase ^ (rla & 7)) * 8)];
                bf[i] = *(const bf16x8*)&Bs[rlb * 64 + ((cbase ^ (rlb & 7)) * 8)];
            }
#pragma unroll
            for (int i = 0; i < 4; ++i)
#pragma unroll
                for (int j = 0; j < 4; ++j)
                    acc[i][j] = __builtin_amdgcn_mfma_f32_16x16x32_bf16(af[i], bf[j], acc[i][j], 0, 0, 0);
        }
        __syncthreads();
    }

    int mvalid = cnt - mtile * 128; if (mvalid > 128) mvalid = 128;
#pragma unroll
    for (int i = 0; i < 4; ++i)
#pragma unroll
        for (int r = 0; r < 4; ++r) {
            int rl = wm * 64 + i * 16 + quad * 4 + r;
            if (rl < mvalid) {
                int rowg = rowstart + rl;
                unsigned short* yrow = Ybuf + (size_t)rowg * DIM + ntile * 128 + wn * 64 + (lane & 15);
#pragma unroll
                for (int j = 0; j < 4; ++j)
                    yrow[j * 16] = f2bf(acc[i][j][r]);
            }
        }
}

// ---------------- combine: out[n] = w0*Y[row0] + w1*Y[row1] --------------
__global__ void combine_kernel(const unsigned short* __restrict__ Ybuf,
                               const int* __restrict__ row_of_a,
                               const float* __restrict__ a_w,
                               float* __restrict__ out) {
    int n = blockIdx.x, t = threadIdx.x;                 // 256 threads, DIM/4
    int r0 = row_of_a[2 * n], r1 = row_of_a[2 * n + 1];
    float w0 = a_w[2 * n], w1 = a_w[2 * n + 1];
    ushort4 y0 = *(const ushort4*)(Ybuf + (size_t)r0 * DIM + t * 4);
    ushort4 y1 = *(const ushort4*)(Ybuf + (size_t)r1 * DIM + t * 4);
    float4 o;
    o.x = w0 * bf2f(y0.x) + w1 * bf2f(y1.x);
    o.y = w0 * bf2f(y0.y) + w1 * bf2f(y1.y);
    o.z = w0 * bf2f(y0.z) + w1 * bf2f(y1.z);
    o.w = w0 * bf2f(y0.w) + w1 * bf2f(y1.w);
    *(float4*)(out + (size_t)n * DIM + t * 4) = o;
}

// ---------------- launch -------------------------------------------------
extern "C" void kernel_launch(void* const* d_in, const int* in_sizes, int n_in,
                              void* d_out, int out_size, void* d_ws, size_t ws_size,
                              hipStream_t stream) {
    const float* x  = (const float*)d_in[0];
    const float* Wg = (const float*)d_in[1];
    const float* W1 = (const float*)d_in[2];
    const float* W2 = (const float*)d_in[3];
    const float* W3 = (const float*)d_in[4];
    float* out = (float*)d_out;

    char* ws = (char*)d_ws;
    size_t off = 0;
    auto alloc = [&](size_t bytes) -> void* {
        void* p = ws + off;
        off = (off + bytes + 255) & ~(size_t)255;
        return p;
    };
    int*   counts      = (int*)alloc(NEXP * 4);
    int*   a_exp       = (int*)alloc(NROW * 4);
    int*   a_rank      = (int*)alloc(NROW * 4);
    float* a_w         = (float*)alloc(NROW * 4);
    int*   row_of_a    = (int*)alloc(NROW * 4);
    unsigned short* XG   = (unsigned short*)alloc((size_t)NROW * DIM * 2);
    unsigned short* Hbuf = (unsigned short*)alloc((size_t)NROW * HPAD * 2);
    unsigned short* W1b  = (unsigned short*)alloc((size_t)NEXP * HPAD * DIM * 2);
    unsigned short* W3b  = (unsigned short*)alloc((size_t)NEXP * HPAD * DIM * 2);
    unsigned short* W2b  = (unsigned short*)alloc((size_t)NEXP * DIM * HPAD * 2);
    // Ybuf bf16 (16.8 MB) aliases W1b (46.1 MB): W1b is dead once gemm1 completes.
    unsigned short* Ybuf = (unsigned short*)W1b;

    hipMemsetAsync(counts, 0, NEXP * 4, stream);

    prep2_kernel<<<PREP_BLOCKS, 256, 0, stream>>>(
        x, Wg, W1, W2, W3, W1b, W2b, W3b, counts, a_exp, a_rank, a_w);
    gather_kernel<<<NROW / 2, 256, 0, stream>>>(x, a_exp, a_rank, counts, XG, row_of_a);

    gemm1_kernel<<<dim3(HPAD / 64, 64, NEXP), 256, 0, stream>>>(
        XG, W1b, W3b, counts, Hbuf);
    gemm2_kernel<<<dim3(DIM / 128, 64, NEXP), 256, 0, stream>>>(
        Hbuf, W2b, counts, Ybuf);
    combine_kernel<<<NTOK, 256, 0, stream>>>(Ybuf, row_of_a, a_w, out);
}